// Round 6
// baseline (5435.415 us; speedup 1.0000x reference)
//
#include <hip/hip_runtime.h>
#include <hip/hip_fp16.h>

// ---------------- dimensions ----------------
constexpr int T_IN = 4096, W_IN = 128;
constexpr int H1 = 4092, W1 = 124, C1 = 16;
constexpr int H2 = 4088, W2 = 120, C2 = 32;
constexpr int H3 = 4084, W3 = 116, C3 = 64;
constexpr int HP = 4080, WPW = 58;      // pooled
constexpr int KF = 3712;                // 64*58 flattened features

typedef float f32x16 __attribute__((ext_vector_type(16)));

// ---------------- conv1: 1 -> 16 ----------------
__global__ __launch_bounds__(256) void conv1_k(const float* __restrict__ x,
        const float* __restrict__ w, const float* __restrict__ b,
        float* __restrict__ out) {
    int pos = blockIdx.x * 256 + threadIdx.x;
    if (pos >= H1 * W1) return;
    int h = pos / W1, wi = pos - h * W1;
    float p[25];
#pragma unroll
    for (int i = 0; i < 5; i++)
#pragma unroll
        for (int j = 0; j < 5; j++)
            p[i * 5 + j] = x[(h + i) * W_IN + wi + j];
#pragma unroll
    for (int c = 0; c < C1; c++) {
        float acc = b[c];
#pragma unroll
        for (int k = 0; k < 25; k++) acc = fmaf(p[k], w[c * 25 + k], acc);
        out[(size_t)c * (H1 * W1) + pos] = acc;
    }
}

// ---------------- conv2: 16 -> 32 (packed weights [(ci*25+k)*32+co]) ------
__global__ __launch_bounds__(256) void conv2_k(const float* __restrict__ in,
        const float* __restrict__ wp, const float* __restrict__ b,
        float* __restrict__ out) {
    int pos = blockIdx.x * 256 + threadIdx.x;
    if (pos >= H2 * W2) return;
    int h = pos / W2, wi = pos - h * W2;
    float acc[C2];
#pragma unroll
    for (int co = 0; co < C2; co++) acc[co] = b[co];
#pragma unroll 1
    for (int ci = 0; ci < C1; ci++) {
        float p[25];
#pragma unroll
        for (int i = 0; i < 5; i++)
#pragma unroll
            for (int j = 0; j < 5; j++)
                p[i * 5 + j] = in[(size_t)ci * (H1 * W1) + (h + i) * W1 + wi + j];
#pragma unroll
        for (int k = 0; k < 25; k++) {
            const float* wr = wp + (ci * 25 + k) * C2;
#pragma unroll
            for (int co = 0; co < C2; co++) acc[co] = fmaf(p[k], wr[co], acc[co]);
        }
    }
#pragma unroll
    for (int co = 0; co < C2; co++) out[(size_t)co * (H2 * W2) + pos] = acc[co];
}

// ---------------- conv3: 32 -> 64, fp16 output ----------------
__global__ __launch_bounds__(256) void conv3_k(const float* __restrict__ in,
        const float* __restrict__ wp, const float* __restrict__ b,
        __half* __restrict__ out) {
    int pos = blockIdx.x * 256 + threadIdx.x;
    if (pos >= H3 * W3) return;
    int h = pos / W3, wi = pos - h * W3;
    float acc[C3];
#pragma unroll
    for (int co = 0; co < C3; co++) acc[co] = b[co];
#pragma unroll 1
    for (int ci = 0; ci < C2; ci++) {
        float p[25];
#pragma unroll
        for (int i = 0; i < 5; i++)
#pragma unroll
            for (int j = 0; j < 5; j++)
                p[i * 5 + j] = in[(size_t)ci * (H2 * W2) + (h + i) * W2 + wi + j];
#pragma unroll
        for (int k = 0; k < 25; k++) {
            const float* wr = wp + (ci * 25 + k) * C3;
#pragma unroll
            for (int co = 0; co < C3; co++) acc[co] = fmaf(p[k], wr[co], acc[co]);
        }
    }
#pragma unroll
    for (int co = 0; co < C3; co++)
        out[(size_t)co * (H3 * W3) + pos] = __float2half(acc[co]);
}

// ---------------- maxpool 5x2 stride 1,2 ----------------
__global__ __launch_bounds__(256) void pool_k(const __half* __restrict__ in,
        float* __restrict__ out) {
    int idx = blockIdx.x * 256 + threadIdx.x;
    if (idx >= C3 * HP * WPW) return;
    int w = idx % WPW; int rest = idx / WPW; int h = rest % HP; int c = rest / HP;
    const __half* base = in + (size_t)c * (H3 * W3) + (size_t)h * W3 + 2 * w;
    float m = -1e30f;
#pragma unroll
    for (int i = 0; i < 5; i++)
#pragma unroll
        for (int j = 0; j < 2; j++)
            m = fmaxf(m, __half2float(base[(size_t)i * W3 + j]));
    out[idx] = m;   // layout == flat view (HP, 3712)
}

// ---------------- lin1: (4080 x 3712) @ Wt(3712 x 64), K-split + atomics ---
__global__ __launch_bounds__(256) void lin1_k(const float* __restrict__ X,
        const float* __restrict__ Wt, float* __restrict__ L) {
    __shared__ alignas(16) float Xs[64][68];
    int tid = threadIdx.x;
    int j = tid & 63, mg = tid >> 6;
    int m0 = blockIdx.x * 64;
    int c0 = blockIdx.y * 15;
    int c1 = (c0 + 15 < 58) ? c0 + 15 : 58;
    float acc[16];
#pragma unroll
    for (int i = 0; i < 16; i++) acc[i] = 0.f;
    for (int cc = c0; cc < c1; cc++) {
        int k0 = cc * 64;
        __syncthreads();
#pragma unroll
        for (int tix = 0; tix < 16; tix++) {
            int idx = tid + tix * 256;
            int mm = idx >> 6, kk = idx & 63;
            int m = m0 + mm;
            Xs[kk][mm] = (m < HP) ? X[(size_t)m * KF + k0 + kk] : 0.f;
        }
        __syncthreads();
#pragma unroll 4
        for (int k = 0; k < 64; k++) {
            float wv = Wt[(size_t)(k0 + k) * 64 + j];
            const float4* xr = (const float4*)&Xs[k][mg * 16];
            float4 x0 = xr[0], x1 = xr[1], x2 = xr[2], x3 = xr[3];
            acc[0] = fmaf(x0.x, wv, acc[0]);  acc[1] = fmaf(x0.y, wv, acc[1]);
            acc[2] = fmaf(x0.z, wv, acc[2]);  acc[3] = fmaf(x0.w, wv, acc[3]);
            acc[4] = fmaf(x1.x, wv, acc[4]);  acc[5] = fmaf(x1.y, wv, acc[5]);
            acc[6] = fmaf(x1.z, wv, acc[6]);  acc[7] = fmaf(x1.w, wv, acc[7]);
            acc[8] = fmaf(x2.x, wv, acc[8]);  acc[9] = fmaf(x2.y, wv, acc[9]);
            acc[10] = fmaf(x2.z, wv, acc[10]); acc[11] = fmaf(x2.w, wv, acc[11]);
            acc[12] = fmaf(x3.x, wv, acc[12]); acc[13] = fmaf(x3.y, wv, acc[13]);
            acc[14] = fmaf(x3.z, wv, acc[14]); acc[15] = fmaf(x3.w, wv, acc[15]);
        }
    }
#pragma unroll
    for (int mm = 0; mm < 16; mm++) {
        int m = m0 + mg * 16 + mm;
        if (m < HP) atomicAdd(&L[(size_t)m * 64 + j], acc[mm]);
    }
}

// ---------------- gi = L @ wih^T + (bih + wih@l1b) ----------------
__global__ __launch_bounds__(192) void gi_k(const float* __restrict__ L,
        const float* __restrict__ wiht, const float* __restrict__ bc,
        float* __restrict__ gi) {
    __shared__ alignas(16) float Ls[64];
    int m = blockIdx.x, g = threadIdx.x;
    if (g < 64) Ls[g] = L[(size_t)m * 64 + g];
    __syncthreads();
    float acc = bc[g];
#pragma unroll
    for (int k = 0; k < 64; k++) acc = fmaf(Ls[k], wiht[k * 192 + g], acc);
    gi[(size_t)m * 192 + g] = acc;
}

// ---------------- GRU: 2 blocks x 1 wave, LDS h-broadcast ----------------
// Weights in 12 f32x16 register tuples (ext_vector = single SSA value =
// 16 contiguous VGPRs; spilling one costs a 16-wide store, so RA keeps
// them resident). gi prefetch depth 2 (unroll x2) to cover ~900cy HBM
// latency with a ~650cy step.
__global__ __launch_bounds__(64, 1) void gru_k(const float* __restrict__ gi0,
        const float* __restrict__ gi1, const float* __restrict__ whh,
        const float* __restrict__ bhh, float* __restrict__ e,
        float* __restrict__ t) {
    const float* gi = blockIdx.x ? gi1 : gi0;
    float* out = blockIdx.x ? t : e;
    const int r = threadIdx.x;           // hidden index, 0..63
    const f32x16* wrp = (const f32x16*)(whh + (size_t)r * 64);
    const f32x16* wzp = (const f32x16*)(whh + (size_t)(64 + r) * 64);
    const f32x16* wnp = (const f32x16*)(whh + (size_t)(128 + r) * 64);
    f32x16 wr0 = wrp[0], wr1 = wrp[1], wr2 = wrp[2], wr3 = wrp[3];
    f32x16 wz0 = wzp[0], wz1 = wzp[1], wz2 = wzp[2], wz3 = wzp[3];
    f32x16 wn0 = wnp[0], wn1 = wnp[1], wn2 = wnp[2], wn3 = wnp[3];
    float bh_r = bhh[r], bh_z = bhh[64 + r], bh_n = bhh[128 + r];
    __shared__ alignas(64) float hs[64];
    const f32x16* hsv = (const f32x16*)hs;
    float h = 0.f;
    hs[r] = 0.f;
    asm volatile("" ::: "memory");       // LDS write ordered before loop reads

#define GRU_STEP(GA, GB, GC, MIDX, PFIDX) do {                                \
    f32x16 hv0 = hsv[0], hv1 = hsv[1], hv2 = hsv[2], hv3 = hsv[3];            \
    float gr = GA, gz = GB, gn = GC;                                          \
    if ((PFIDX) < HP) {                                                       \
        const float* gp = gi + (size_t)(PFIDX) * 192;                         \
        GA = gp[r]; GB = gp[64 + r]; GC = gp[128 + r];                        \
    }                                                                         \
    float ar0 = 0.f, ar1 = 0.f, ar2 = 0.f, ar3 = 0.f;                         \
    float az0 = 0.f, az1 = 0.f, az2 = 0.f, az3 = 0.f;                         \
    float an0 = 0.f, an1 = 0.f, an2 = 0.f, an3 = 0.f;                         \
    _Pragma("unroll")                                                         \
    for (int i = 0; i < 16; i++) {                                            \
        ar0 = fmaf(wr0[i], hv0[i], ar0); az0 = fmaf(wz0[i], hv0[i], az0);     \
        an0 = fmaf(wn0[i], hv0[i], an0);                                      \
        ar1 = fmaf(wr1[i], hv1[i], ar1); az1 = fmaf(wz1[i], hv1[i], az1);     \
        an1 = fmaf(wn1[i], hv1[i], an1);                                      \
        ar2 = fmaf(wr2[i], hv2[i], ar2); az2 = fmaf(wz2[i], hv2[i], az2);     \
        an2 = fmaf(wn2[i], hv2[i], an2);                                      \
        ar3 = fmaf(wr3[i], hv3[i], ar3); az3 = fmaf(wz3[i], hv3[i], az3);     \
        an3 = fmaf(wn3[i], hv3[i], an3);                                      \
    }                                                                         \
    float ar = (ar0 + ar1) + (ar2 + ar3);                                     \
    float az = (az0 + az1) + (az2 + az3);                                     \
    float an = (an0 + an1) + (an2 + an3);                                     \
    float rg = 1.f / (1.f + __expf(-(gr + ar + bh_r)));                       \
    float zg = 1.f / (1.f + __expf(-(gz + az + bh_z)));                       \
    float pre = gn + rg * (an + bh_n);                                        \
    float ex = __expf(2.f * pre);                                             \
    float nn = 1.f - 2.f / (ex + 1.f);                                        \
    h = (1.f - zg) * nn + zg * h;                                             \
    hs[r] = h;                                                                \
    asm volatile("" ::: "memory");                                            \
    out[(size_t)(MIDX) * 64 + r] = h;                                         \
} while (0)

    float a0 = gi[r], a1 = gi[64 + r], a2 = gi[128 + r];
    float b0 = gi[192 + r], b1 = gi[256 + r], b2 = gi[320 + r];
#pragma unroll 1
    for (int m = 0; m < HP; m += 2) {
        GRU_STEP(a0, a1, a2, m, m + 2);
        GRU_STEP(b0, b1, b2, m + 1, m + 3);
    }
#undef GRU_STEP
}

// ---------------- alignment column stats (online softmax over m) ----------
__global__ __launch_bounds__(256) void astat_k(const float* __restrict__ e,
        const float* __restrict__ t, float* __restrict__ pM,
        float* __restrict__ pZ) {
    __shared__ alignas(16) float Ts[64][68];
    __shared__ float Ms[4][64], Zs[4][64];
    int tid = threadIdx.x;
    int nl = tid & 63, ms = tid >> 6;
    int n0 = blockIdx.x * 64;
#pragma unroll
    for (int i = 0; i < 16; i++) {
        int idx = tid + i * 256;
        int rr = idx >> 6, kk = idx & 63;
        int n = n0 + rr;
        Ts[rr][kk] = (n < HP) ? t[(size_t)n * 64 + kk] : 0.f;
    }
    __syncthreads();
    float M = -1e30f, Z = 0.f;
    int m0 = blockIdx.y * 510;
    const float4* Trow = (const float4*)&Ts[nl][0];
    for (int m = m0 + ms; m < m0 + 510; m += 4) {
        const float4* er = (const float4*)(e + (size_t)m * 64);
        float a0 = 0, a1 = 0, a2 = 0, a3 = 0;
#pragma unroll
        for (int i = 0; i < 16; i++) {
            float4 evv = er[i], tv = Trow[i];
            a0 = fmaf(evv.x, tv.x, a0); a1 = fmaf(evv.y, tv.y, a1);
            a2 = fmaf(evv.z, tv.z, a2); a3 = fmaf(evv.w, tv.w, a3);
        }
        float s = (a0 + a1) + (a2 + a3);
        float nM = fmaxf(M, s);
        Z = Z * __expf(M - nM) + __expf(s - nM);
        M = nM;
    }
    Ms[ms][nl] = M; Zs[ms][nl] = Z;
    __syncthreads();
    if (ms == 0) {
#pragma unroll
        for (int i = 1; i < 4; i++) {
            float m2 = Ms[i][nl], z2 = Zs[i][nl];
            float nM = fmaxf(M, m2);
            Z = Z * __expf(M - nM) + z2 * __expf(m2 - nM);
            M = nM;
        }
        int n = n0 + nl;
        if (n < HP) { pM[(size_t)blockIdx.y * HP + n] = M; pZ[(size_t)blockIdx.y * HP + n] = Z; }
    }
}

// ---------------- attention logits ----------------
__global__ __launch_bounds__(256) void attnlog_k(const float* __restrict__ e,
        const float* __restrict__ aw, const float* __restrict__ ab,
        float* __restrict__ alog) {
    int m = blockIdx.x * 256 + threadIdx.x;
    if (m >= HP) return;
    float acc = ab[0];
    const float4* er = (const float4*)(e + (size_t)m * 64);
    const float4* ar = (const float4*)aw;
#pragma unroll
    for (int i = 0; i < 16; i++) {
        float4 evv = er[i], av = ar[i];
        acc += evv.x * av.x + evv.y * av.y + evv.z * av.z + evv.w * av.w;
    }
    alog[m] = acc;
}

// ---------------- reduce partial stats + attn softmax stats ---------------
__global__ __launch_bounds__(256) void reduce_k(const float* __restrict__ pM,
        const float* __restrict__ pZ, float* __restrict__ Mn,
        float* __restrict__ Zn, const float* __restrict__ alog,
        float* __restrict__ scal) {
    int tid = threadIdx.x;
    if (blockIdx.x < 16) {
        int n = blockIdx.x * 256 + tid;
        if (n >= HP) return;
        float M = pM[n], Z = pZ[n];
#pragma unroll
        for (int y = 1; y < 8; y++) {
            float m2 = pM[(size_t)y * HP + n], z2 = pZ[(size_t)y * HP + n];
            float nM = fmaxf(M, m2);
            Z = Z * __expf(M - nM) + z2 * __expf(m2 - nM);
            M = nM;
        }
        Mn[n] = M; Zn[n] = Z;
    } else {
        __shared__ float red[256];
        float m = -1e30f;
        for (int i = tid; i < HP; i += 256) m = fmaxf(m, alog[i]);
        red[tid] = m; __syncthreads();
        for (int s = 128; s > 0; s >>= 1) {
            if (tid < s) red[tid] = fmaxf(red[tid], red[tid + s]);
            __syncthreads();
        }
        float Ma = red[0]; __syncthreads();
        float z = 0.f;
        for (int i = tid; i < HP; i += 256) z += __expf(alog[i] - Ma);
        red[tid] = z; __syncthreads();
        for (int s = 128; s > 0; s >>= 1) {
            if (tid < s) red[tid] += red[tid + s];
            __syncthreads();
        }
        if (tid == 0) { scal[0] = Ma; scal[1] = red[0]; }
    }
}

// ---------------- Wmat rows m<64 ----------------
__global__ __launch_bounds__(256) void wmat_k(const float* __restrict__ e,
        const float* __restrict__ t, const float* __restrict__ Mn,
        const float* __restrict__ Zn, float* __restrict__ Wm) {
    __shared__ alignas(16) float Es[64][68];
    int tid = threadIdx.x;
#pragma unroll
    for (int i = 0; i < 16; i++) {
        int idx = tid + i * 256;
        int rr = idx >> 6, kk = idx & 63;
        Es[rr][kk] = e[(size_t)rr * 64 + kk];
    }
    __syncthreads();
    int n = blockIdx.x * 256 + tid;
    if (n >= HP) return;
    float tn[64];
    const float4* tr = (const float4*)(t + (size_t)n * 64);
    float4* tn4 = (float4*)tn;
#pragma unroll
    for (int i = 0; i < 16; i++) tn4[i] = tr[i];
    float mM = Mn[n], iZ = 1.f / Zn[n];
#pragma unroll 1
    for (int m = 0; m < 64; m++) {
        const float4* Er = (const float4*)&Es[m][0];
        float a0 = 0, a1 = 0, a2 = 0, a3 = 0;
#pragma unroll
        for (int i = 0; i < 16; i++) {
            float4 evv = Er[i], tv = tn4[i];
            a0 = fmaf(evv.x, tv.x, a0); a1 = fmaf(evv.y, tv.y, a1);
            a2 = fmaf(evv.z, tv.z, a2); a3 = fmaf(evv.w, tv.w, a3);
        }
        float s = (a0 + a1) + (a2 + a3);
        Wm[(size_t)m * HP + n] = __expf(s - mM) * iZ;
    }
}

// ---------------- t_prim = Wm(64 x 4080) @ t(4080 x 64), K-split atomics ---
__global__ __launch_bounds__(256) void tprim_k(const float* __restrict__ Wm,
        const float* __restrict__ t, float* __restrict__ tp) {
    __shared__ float Ws[64][64];
    __shared__ float Ts[64][64];
    int tid = threadIdx.x;
    int n0 = blockIdx.x * 64;
#pragma unroll
    for (int i = 0; i < 16; i++) {
        int idx = tid + i * 256;
        int r = idx >> 6, c = idx & 63;
        Ws[r][c] = (n0 + c < HP) ? Wm[(size_t)r * HP + n0 + c] : 0.f;
        Ts[r][c] = (n0 + r < HP) ? t[(size_t)(n0 + r) * 64 + c] : 0.f;
    }
    __syncthreads();
    int d = tid & 63, mg = tid >> 6;
    float acc[16];
#pragma unroll
    for (int i = 0; i < 16; i++) acc[i] = 0.f;
    for (int k = 0; k < 64; k++) {
        float tv = Ts[k][d];
#pragma unroll
        for (int mm = 0; mm < 16; mm++) acc[mm] = fmaf(Ws[mg * 16 + mm][k], tv, acc[mm]);
    }
#pragma unroll
    for (int mm = 0; mm < 16; mm++)
        atomicAdd(&tp[(size_t)(mg * 16 + mm) * 64 + d], acc[mm]);
}

// ---------------- epilogue ----------------
__global__ __launch_bounds__(256) void final_k(const float* __restrict__ tp,
        const float* __restrict__ e, const float* __restrict__ alog,
        const float* __restrict__ scal, const float* __restrict__ l3w,
        const float* __restrict__ l3b, const float* __restrict__ cw,
        const float* __restrict__ cb, float* __restrict__ out) {
    __shared__ float r1[64], hid[128];
    int tid = threadIdx.x;
    float Ma = scal[0], iZa = 1.f / scal[1];
    if (tid < 64) {
        float acc = 0.f;
        for (int m = 0; m < 64; m++) {
            float a = __expf(alog[m] - Ma) * iZa;
            acc += fabsf(tp[m * 64 + tid] - e[m * 64 + tid]) * a;
        }
        r1[tid] = fmaxf(acc, 0.f);
    }
    __syncthreads();
    if (tid < 128) {
        float acc = l3b[tid];
        for (int d = 0; d < 64; d++) acc = fmaf(r1[d], l3w[tid * 64 + d], acc);
        hid[tid] = fmaxf(acc, 0.f);
    }
    __syncthreads();
    if (tid < 2) {
        float acc = cb[tid];
        for (int j = 0; j < 128; j++) acc = fmaf(hid[j], cw[tid * 128 + j], acc);
        out[tid] = acc;
    }
}

// ---------------- weight packing ----------------
__global__ __launch_bounds__(256) void transpose_l1w_k(const float* __restrict__ w,
        float* __restrict__ wt) {
    int idx = blockIdx.x * 256 + threadIdx.x;
    if (idx >= KF * 64) return;
    int k = idx >> 6, j = idx & 63;
    wt[idx] = w[(size_t)j * KF + k];
}
__global__ __launch_bounds__(256) void pack_w2_k(const float* __restrict__ w,
        float* __restrict__ wp) {
    int idx = blockIdx.x * 256 + threadIdx.x;
    if (idx >= 12800) return;
    int co = idx & 31, rest = idx >> 5;
    wp[idx] = w[co * 400 + rest];
}
__global__ __launch_bounds__(256) void pack_w3_k(const float* __restrict__ w,
        float* __restrict__ wp) {
    int idx = blockIdx.x * 256 + threadIdx.x;
    if (idx >= 51200) return;
    int co = idx & 63, rest = idx >> 6;
    wp[idx] = w[co * 800 + rest];
}
__global__ __launch_bounds__(256) void pack_wih_k(const float* __restrict__ wih,
        const float* __restrict__ bih, const float* __restrict__ l1b,
        float* __restrict__ wiht, float* __restrict__ bc) {
    int idx = blockIdx.x * 256 + threadIdx.x;
    if (idx < 12288) {
        int g = idx % 192, k = idx / 192;
        wiht[idx] = wih[g * 64 + k];
    }
    if (idx < 192) {
        float acc = bih[idx];
#pragma unroll
        for (int k = 0; k < 64; k++) acc = fmaf(wih[idx * 64 + k], l1b[k], acc);
        bc[idx] = acc;
    }
}

// ---------------- host ----------------
extern "C" void kernel_launch(void* const* d_in, const int* in_sizes, int n_in,
                              void* d_out, int out_size, void* d_ws, size_t ws_size,
                              hipStream_t stream) {
    const float* ev    = (const float*)d_in[0];
    const float* tmpl  = (const float*)d_in[1];
    const float* w1    = (const float*)d_in[2];
    const float* b1    = (const float*)d_in[3];
    const float* w2    = (const float*)d_in[4];
    const float* b2    = (const float*)d_in[5];
    const float* w3    = (const float*)d_in[6];
    const float* b3    = (const float*)d_in[7];
    const float* l1w   = (const float*)d_in[8];
    const float* l1b   = (const float*)d_in[9];
    const float* wih   = (const float*)d_in[10];
    const float* whh   = (const float*)d_in[11];
    const float* bih   = (const float*)d_in[12];
    const float* bhh   = (const float*)d_in[13];
    const float* aw    = (const float*)d_in[14];
    const float* ab    = (const float*)d_in[15];
    const float* l3w   = (const float*)d_in[16];
    const float* l3b   = (const float*)d_in[17];
    const float* cw    = (const float*)d_in[18];
    const float* cb    = (const float*)d_in[19];
    float* out = (float*)d_out;
    (void)in_sizes; (void)n_in; (void)out_size;

    char* ws = (char*)d_ws;
    size_t off = 0;
    auto alloc = [&](size_t bytes) -> char* {
        char* p = ws + off;
        off += (bytes + 255) & ~(size_t)255;
        return p;
    };
    size_t szA = (size_t)C3 * H3 * W3 * 2;                 // fp16 conv3 out
    size_t szA1 = (size_t)C1 * H1 * W1 * 4;                // fp32 conv1 out
    if (szA1 > szA) szA = szA1;
    char*  A    = alloc(szA);
    float* B    = (float*)alloc((size_t)C2 * H2 * W2 * 4); // conv2 out / pooled
    float* Wt   = (float*)alloc((size_t)KF * 64 * 4);
    float* w2p  = (float*)alloc(12800 * 4);
    float* w3p  = (float*)alloc(51200 * 4);
    float* wiht = (float*)alloc(12288 * 4);
    float* bc   = (float*)alloc(256 * 4);
    float* L    = (float*)alloc((size_t)HP * 64 * 4);
    float* gi0  = (float*)alloc((size_t)HP * 192 * 4);
    float* gi1  = (float*)alloc((size_t)HP * 192 * 4);
    float* ebuf = (float*)alloc((size_t)HP * 64 * 4);
    float* tbuf = (float*)alloc((size_t)HP * 64 * 4);
    float* pM   = (float*)alloc((size_t)8 * HP * 4);
    float* pZ   = (float*)alloc((size_t)8 * HP * 4);
    float* Mn   = (float*)alloc(HP * 4);
    float* Zn   = (float*)alloc(HP * 4);
    float* Wm   = (float*)alloc((size_t)64 * HP * 4);
    float* alog = (float*)alloc(HP * 4);
    float* tpm  = (float*)alloc(64 * 64 * 4);
    float* scal = (float*)alloc(256);
    if (off > ws_size) return;   // workspace too small: bail loudly (validation fails)

    transpose_l1w_k<<<dim3((KF * 64 + 255) / 256), dim3(256), 0, stream>>>(l1w, Wt);
    pack_w2_k<<<dim3(50), dim3(256), 0, stream>>>(w2, w2p);
    pack_w3_k<<<dim3(200), dim3(256), 0, stream>>>(w3, w3p);
    pack_wih_k<<<dim3(48), dim3(256), 0, stream>>>(wih, bih, l1b, wiht, bc);

    for (int bsel = 0; bsel < 2; bsel++) {
        const float* xin = bsel ? tmpl : ev;
        float* gib = bsel ? gi1 : gi0;
        conv1_k<<<dim3((H1 * W1 + 255) / 256), dim3(256), 0, stream>>>(xin, w1, b1, (float*)A);
        conv2_k<<<dim3((H2 * W2 + 255) / 256), dim3(256), 0, stream>>>((const float*)A, w2p, b2, B);
        conv3_k<<<dim3((H3 * W3 + 255) / 256), dim3(256), 0, stream>>>(B, w3p, b3, (__half*)A);
        pool_k<<<dim3((C3 * HP * WPW + 255) / 256), dim3(256), 0, stream>>>((const __half*)A, B);
        hipMemsetAsync(L, 0, (size_t)HP * 64 * 4, stream);
        lin1_k<<<dim3(64, 4), dim3(256), 0, stream>>>(B, Wt, L);
        gi_k<<<dim3(HP), dim3(192), 0, stream>>>(L, wiht, bc, gib);
    }
    gru_k<<<dim3(2), dim3(64), 0, stream>>>(gi0, gi1, whh, bhh, ebuf, tbuf);
    astat_k<<<dim3(64, 8), dim3(256), 0, stream>>>(ebuf, tbuf, pM, pZ);
    attnlog_k<<<dim3(16), dim3(256), 0, stream>>>(ebuf, aw, ab, alog);
    reduce_k<<<dim3(17), dim3(256), 0, stream>>>(pM, pZ, Mn, Zn, alog, scal);
    wmat_k<<<dim3(16), dim3(256), 0, stream>>>(ebuf, tbuf, Mn, Zn, Wm);
    hipMemsetAsync(tpm, 0, 64 * 64 * 4, stream);
    tprim_k<<<dim3(64), dim3(256), 0, stream>>>(Wm, tbuf, tpm);
    final_k<<<dim3(1), dim3(256), 0, stream>>>(tpm, ebuf, alog, scal, l3w, l3b, cw, cb, out);
}

// Round 7
// 4730.526 us; speedup vs baseline: 1.1490x; 1.1490x over previous
//
#include <hip/hip_runtime.h>
#include <hip/hip_fp16.h>

// ---------------- dimensions ----------------
constexpr int T_IN = 4096, W_IN = 128;
constexpr int H1 = 4092, W1 = 124, C1 = 16;
constexpr int H2 = 4088, W2 = 120, C2 = 32;
constexpr int H3 = 4084, W3 = 116, C3 = 64;
constexpr int HP = 4080, WPW = 58;      // pooled
constexpr int KF = 3712;                // 64*58 flattened features

typedef float f32x16 __attribute__((ext_vector_type(16)));

// ---------------- conv1: 1 -> 16 ----------------
__global__ __launch_bounds__(256) void conv1_k(const float* __restrict__ x,
        const float* __restrict__ w, const float* __restrict__ b,
        float* __restrict__ out) {
    int pos = blockIdx.x * 256 + threadIdx.x;
    if (pos >= H1 * W1) return;
    int h = pos / W1, wi = pos - h * W1;
    float p[25];
#pragma unroll
    for (int i = 0; i < 5; i++)
#pragma unroll
        for (int j = 0; j < 5; j++)
            p[i * 5 + j] = x[(h + i) * W_IN + wi + j];
#pragma unroll
    for (int c = 0; c < C1; c++) {
        float acc = b[c];
#pragma unroll
        for (int k = 0; k < 25; k++) acc = fmaf(p[k], w[c * 25 + k], acc);
        out[(size_t)c * (H1 * W1) + pos] = acc;
    }
}

// ---------------- conv2: 16 -> 32 (packed weights [(ci*25+k)*32+co]) ------
__global__ __launch_bounds__(256) void conv2_k(const float* __restrict__ in,
        const float* __restrict__ wp, const float* __restrict__ b,
        float* __restrict__ out) {
    int pos = blockIdx.x * 256 + threadIdx.x;
    if (pos >= H2 * W2) return;
    int h = pos / W2, wi = pos - h * W2;
    float acc[C2];
#pragma unroll
    for (int co = 0; co < C2; co++) acc[co] = b[co];
#pragma unroll 1
    for (int ci = 0; ci < C1; ci++) {
        float p[25];
#pragma unroll
        for (int i = 0; i < 5; i++)
#pragma unroll
            for (int j = 0; j < 5; j++)
                p[i * 5 + j] = in[(size_t)ci * (H1 * W1) + (h + i) * W1 + wi + j];
#pragma unroll
        for (int k = 0; k < 25; k++) {
            const float* wr = wp + (ci * 25 + k) * C2;
#pragma unroll
            for (int co = 0; co < C2; co++) acc[co] = fmaf(p[k], wr[co], acc[co]);
        }
    }
#pragma unroll
    for (int co = 0; co < C2; co++) out[(size_t)co * (H2 * W2) + pos] = acc[co];
}

// ---------------- conv3: 32 -> 64, fp16 output ----------------
__global__ __launch_bounds__(256) void conv3_k(const float* __restrict__ in,
        const float* __restrict__ wp, const float* __restrict__ b,
        __half* __restrict__ out) {
    int pos = blockIdx.x * 256 + threadIdx.x;
    if (pos >= H3 * W3) return;
    int h = pos / W3, wi = pos - h * W3;
    float acc[C3];
#pragma unroll
    for (int co = 0; co < C3; co++) acc[co] = b[co];
#pragma unroll 1
    for (int ci = 0; ci < C2; ci++) {
        float p[25];
#pragma unroll
        for (int i = 0; i < 5; i++)
#pragma unroll
            for (int j = 0; j < 5; j++)
                p[i * 5 + j] = in[(size_t)ci * (H2 * W2) + (h + i) * W2 + wi + j];
#pragma unroll
        for (int k = 0; k < 25; k++) {
            const float* wr = wp + (ci * 25 + k) * C3;
#pragma unroll
            for (int co = 0; co < C3; co++) acc[co] = fmaf(p[k], wr[co], acc[co]);
        }
    }
#pragma unroll
    for (int co = 0; co < C3; co++)
        out[(size_t)co * (H3 * W3) + pos] = __float2half(acc[co]);
}

// ---------------- maxpool 5x2 stride 1,2 ----------------
__global__ __launch_bounds__(256) void pool_k(const __half* __restrict__ in,
        float* __restrict__ out) {
    int idx = blockIdx.x * 256 + threadIdx.x;
    if (idx >= C3 * HP * WPW) return;
    int w = idx % WPW; int rest = idx / WPW; int h = rest % HP; int c = rest / HP;
    const __half* base = in + (size_t)c * (H3 * W3) + (size_t)h * W3 + 2 * w;
    float m = -1e30f;
#pragma unroll
    for (int i = 0; i < 5; i++)
#pragma unroll
        for (int j = 0; j < 2; j++)
            m = fmaxf(m, __half2float(base[(size_t)i * W3 + j]));
    out[idx] = m;   // layout == flat view (HP, 3712)
}

// ---------------- lin1: (4080 x 3712) @ Wt(3712 x 64), K-split + atomics ---
__global__ __launch_bounds__(256) void lin1_k(const float* __restrict__ X,
        const float* __restrict__ Wt, float* __restrict__ L) {
    __shared__ alignas(16) float Xs[64][68];
    int tid = threadIdx.x;
    int j = tid & 63, mg = tid >> 6;
    int m0 = blockIdx.x * 64;
    int c0 = blockIdx.y * 15;
    int c1 = (c0 + 15 < 58) ? c0 + 15 : 58;
    float acc[16];
#pragma unroll
    for (int i = 0; i < 16; i++) acc[i] = 0.f;
    for (int cc = c0; cc < c1; cc++) {
        int k0 = cc * 64;
        __syncthreads();
#pragma unroll
        for (int tix = 0; tix < 16; tix++) {
            int idx = tid + tix * 256;
            int mm = idx >> 6, kk = idx & 63;
            int m = m0 + mm;
            Xs[kk][mm] = (m < HP) ? X[(size_t)m * KF + k0 + kk] : 0.f;
        }
        __syncthreads();
#pragma unroll 4
        for (int k = 0; k < 64; k++) {
            float wv = Wt[(size_t)(k0 + k) * 64 + j];
            const float4* xr = (const float4*)&Xs[k][mg * 16];
            float4 x0 = xr[0], x1 = xr[1], x2 = xr[2], x3 = xr[3];
            acc[0] = fmaf(x0.x, wv, acc[0]);  acc[1] = fmaf(x0.y, wv, acc[1]);
            acc[2] = fmaf(x0.z, wv, acc[2]);  acc[3] = fmaf(x0.w, wv, acc[3]);
            acc[4] = fmaf(x1.x, wv, acc[4]);  acc[5] = fmaf(x1.y, wv, acc[5]);
            acc[6] = fmaf(x1.z, wv, acc[6]);  acc[7] = fmaf(x1.w, wv, acc[7]);
            acc[8] = fmaf(x2.x, wv, acc[8]);  acc[9] = fmaf(x2.y, wv, acc[9]);
            acc[10] = fmaf(x2.z, wv, acc[10]); acc[11] = fmaf(x2.w, wv, acc[11]);
            acc[12] = fmaf(x3.x, wv, acc[12]); acc[13] = fmaf(x3.y, wv, acc[13]);
            acc[14] = fmaf(x3.z, wv, acc[14]); acc[15] = fmaf(x3.w, wv, acc[15]);
        }
    }
#pragma unroll
    for (int mm = 0; mm < 16; mm++) {
        int m = m0 + mg * 16 + mm;
        if (m < HP) atomicAdd(&L[(size_t)m * 64 + j], acc[mm]);
    }
}

// ---------------- gi = L @ wih^T + (bih + wih@l1b) ----------------
__global__ __launch_bounds__(192) void gi_k(const float* __restrict__ L,
        const float* __restrict__ wiht, const float* __restrict__ bc,
        float* __restrict__ gi) {
    __shared__ alignas(16) float Ls[64];
    int m = blockIdx.x, g = threadIdx.x;
    if (g < 64) Ls[g] = L[(size_t)m * 64 + g];
    __syncthreads();
    float acc = bc[g];
#pragma unroll
    for (int k = 0; k < 64; k++) acc = fmaf(Ls[k], wiht[k * 192 + g], acc);
    gi[(size_t)m * 192 + g] = acc;
}

// ---------------- GRU: 2 blocks x 3 waves ----------------
// Lane g owns ONE whh row (64 floats = 4 f32x16 = 64 VGPRs; peak live
// ~150 < 256 arch cap, so residency is feasible — unlike all 1-wave
// variants which needed ~280). launch_bounds(192,1) stops the RA from
// capping VGPRs for occupancy. Lanes 0-63 do the gate math (their own
// a_r stays in-register; gi triple prefetched 1 step ahead).
__global__ __launch_bounds__(192, 1) void gru_k(const float* __restrict__ gi0,
        const float* __restrict__ gi1, const float* __restrict__ whh,
        const float* __restrict__ bhh, float* __restrict__ e,
        float* __restrict__ t) {
    const float* gi = blockIdx.x ? gi1 : gi0;
    float* out = blockIdx.x ? t : e;
    const int g = threadIdx.x;           // gate row, 0..191
    const f32x16* wp = (const f32x16*)(whh + (size_t)g * 64);
    f32x16 w0 = wp[0], w1 = wp[1], w2 = wp[2], w3 = wp[3];
    float bh = bhh[g];
    __shared__ alignas(64) float hs[64];
    __shared__ float Ax[192];
    const f32x16* hsv = (const f32x16*)hs;
    float h = 0.f;
    if (g < 64) hs[g] = 0.f;
    __syncthreads();
    float p0 = 0.f, p1 = 0.f, p2 = 0.f;  // gi prefetch (lanes<64 only)
    if (g < 64) { p0 = gi[g]; p1 = gi[64 + g]; p2 = gi[128 + g]; }
#pragma unroll 1
    for (int m = 0; m < HP; m++) {
        f32x16 hv0 = hsv[0], hv1 = hsv[1], hv2 = hsv[2], hv3 = hsv[3];
        float c0 = p0, c1 = p1, c2 = p2;
        if (g < 64 && m + 1 < HP) {
            const float* gp = gi + (size_t)(m + 1) * 192;
            p0 = gp[g]; p1 = gp[64 + g]; p2 = gp[128 + g];
        }
        float a0 = 0.f, a1 = 0.f, a2 = 0.f, a3 = 0.f;
#pragma unroll
        for (int i = 0; i < 16; i++) {
            a0 = fmaf(w0[i], hv0[i], a0);
            a1 = fmaf(w1[i], hv1[i], a1);
            a2 = fmaf(w2[i], hv2[i], a2);
            a3 = fmaf(w3[i], hv3[i], a3);
        }
        float a = (a0 + a1) + (a2 + a3) + bh;
        Ax[g] = a;
        __syncthreads();
        if (g < 64) {
            float az = Ax[64 + g], an = Ax[128 + g];
            float rg = 1.f / (1.f + __expf(-(c0 + a)));
            float zg = 1.f / (1.f + __expf(-(c1 + az)));
            float pre = c2 + rg * an;
            float ex = __expf(2.f * pre);
            float nn = 1.f - 2.f / (ex + 1.f);      // tanh, overflow-safe
            h = (1.f - zg) * nn + zg * h;
            hs[g] = h;
            out[(size_t)m * 64 + g] = h;
        }
        __syncthreads();
    }
}

// ---------------- alignment column stats (online softmax over m) ----------
__global__ __launch_bounds__(256) void astat_k(const float* __restrict__ e,
        const float* __restrict__ t, float* __restrict__ pM,
        float* __restrict__ pZ) {
    __shared__ alignas(16) float Ts[64][68];
    __shared__ float Ms[4][64], Zs[4][64];
    int tid = threadIdx.x;
    int nl = tid & 63, ms = tid >> 6;
    int n0 = blockIdx.x * 64;
#pragma unroll
    for (int i = 0; i < 16; i++) {
        int idx = tid + i * 256;
        int rr = idx >> 6, kk = idx & 63;
        int n = n0 + rr;
        Ts[rr][kk] = (n < HP) ? t[(size_t)n * 64 + kk] : 0.f;
    }
    __syncthreads();
    float M = -1e30f, Z = 0.f;
    int m0 = blockIdx.y * 510;
    const float4* Trow = (const float4*)&Ts[nl][0];
    for (int m = m0 + ms; m < m0 + 510; m += 4) {
        const float4* er = (const float4*)(e + (size_t)m * 64);
        float a0 = 0, a1 = 0, a2 = 0, a3 = 0;
#pragma unroll
        for (int i = 0; i < 16; i++) {
            float4 evv = er[i], tv = Trow[i];
            a0 = fmaf(evv.x, tv.x, a0); a1 = fmaf(evv.y, tv.y, a1);
            a2 = fmaf(evv.z, tv.z, a2); a3 = fmaf(evv.w, tv.w, a3);
        }
        float s = (a0 + a1) + (a2 + a3);
        float nM = fmaxf(M, s);
        Z = Z * __expf(M - nM) + __expf(s - nM);
        M = nM;
    }
    Ms[ms][nl] = M; Zs[ms][nl] = Z;
    __syncthreads();
    if (ms == 0) {
#pragma unroll
        for (int i = 1; i < 4; i++) {
            float m2 = Ms[i][nl], z2 = Zs[i][nl];
            float nM = fmaxf(M, m2);
            Z = Z * __expf(M - nM) + z2 * __expf(m2 - nM);
            M = nM;
        }
        int n = n0 + nl;
        if (n < HP) { pM[(size_t)blockIdx.y * HP + n] = M; pZ[(size_t)blockIdx.y * HP + n] = Z; }
    }
}

// ---------------- attention logits ----------------
__global__ __launch_bounds__(256) void attnlog_k(const float* __restrict__ e,
        const float* __restrict__ aw, const float* __restrict__ ab,
        float* __restrict__ alog) {
    int m = blockIdx.x * 256 + threadIdx.x;
    if (m >= HP) return;
    float acc = ab[0];
    const float4* er = (const float4*)(e + (size_t)m * 64);
    const float4* ar = (const float4*)aw;
#pragma unroll
    for (int i = 0; i < 16; i++) {
        float4 evv = er[i], av = ar[i];
        acc += evv.x * av.x + evv.y * av.y + evv.z * av.z + evv.w * av.w;
    }
    alog[m] = acc;
}

// ---------------- reduce partial stats + attn softmax stats ---------------
__global__ __launch_bounds__(256) void reduce_k(const float* __restrict__ pM,
        const float* __restrict__ pZ, float* __restrict__ Mn,
        float* __restrict__ Zn, const float* __restrict__ alog,
        float* __restrict__ scal) {
    int tid = threadIdx.x;
    if (blockIdx.x < 16) {
        int n = blockIdx.x * 256 + tid;
        if (n >= HP) return;
        float M = pM[n], Z = pZ[n];
#pragma unroll
        for (int y = 1; y < 8; y++) {
            float m2 = pM[(size_t)y * HP + n], z2 = pZ[(size_t)y * HP + n];
            float nM = fmaxf(M, m2);
            Z = Z * __expf(M - nM) + z2 * __expf(m2 - nM);
            M = nM;
        }
        Mn[n] = M; Zn[n] = Z;
    } else {
        __shared__ float red[256];
        float m = -1e30f;
        for (int i = tid; i < HP; i += 256) m = fmaxf(m, alog[i]);
        red[tid] = m; __syncthreads();
        for (int s = 128; s > 0; s >>= 1) {
            if (tid < s) red[tid] = fmaxf(red[tid], red[tid + s]);
            __syncthreads();
        }
        float Ma = red[0]; __syncthreads();
        float z = 0.f;
        for (int i = tid; i < HP; i += 256) z += __expf(alog[i] - Ma);
        red[tid] = z; __syncthreads();
        for (int s = 128; s > 0; s >>= 1) {
            if (tid < s) red[tid] += red[tid + s];
            __syncthreads();
        }
        if (tid == 0) { scal[0] = Ma; scal[1] = red[0]; }
    }
}

// ---------------- Wmat rows m<64 ----------------
__global__ __launch_bounds__(256) void wmat_k(const float* __restrict__ e,
        const float* __restrict__ t, const float* __restrict__ Mn,
        const float* __restrict__ Zn, float* __restrict__ Wm) {
    __shared__ alignas(16) float Es[64][68];
    int tid = threadIdx.x;
#pragma unroll
    for (int i = 0; i < 16; i++) {
        int idx = tid + i * 256;
        int rr = idx >> 6, kk = idx & 63;
        Es[rr][kk] = e[(size_t)rr * 64 + kk];
    }
    __syncthreads();
    int n = blockIdx.x * 256 + tid;
    if (n >= HP) return;
    float tn[64];
    const float4* tr = (const float4*)(t + (size_t)n * 64);
    float4* tn4 = (float4*)tn;
#pragma unroll
    for (int i = 0; i < 16; i++) tn4[i] = tr[i];
    float mM = Mn[n], iZ = 1.f / Zn[n];
#pragma unroll 1
    for (int m = 0; m < 64; m++) {
        const float4* Er = (const float4*)&Es[m][0];
        float a0 = 0, a1 = 0, a2 = 0, a3 = 0;
#pragma unroll
        for (int i = 0; i < 16; i++) {
            float4 evv = Er[i], tv = tn4[i];
            a0 = fmaf(evv.x, tv.x, a0); a1 = fmaf(evv.y, tv.y, a1);
            a2 = fmaf(evv.z, tv.z, a2); a3 = fmaf(evv.w, tv.w, a3);
        }
        float s = (a0 + a1) + (a2 + a3);
        Wm[(size_t)m * HP + n] = __expf(s - mM) * iZ;
    }
}

// ---------------- t_prim = Wm(64 x 4080) @ t(4080 x 64), K-split atomics ---
__global__ __launch_bounds__(256) void tprim_k(const float* __restrict__ Wm,
        const float* __restrict__ t, float* __restrict__ tp) {
    __shared__ float Ws[64][64];
    __shared__ float Ts[64][64];
    int tid = threadIdx.x;
    int n0 = blockIdx.x * 64;
#pragma unroll
    for (int i = 0; i < 16; i++) {
        int idx = tid + i * 256;
        int r = idx >> 6, c = idx & 63;
        Ws[r][c] = (n0 + c < HP) ? Wm[(size_t)r * HP + n0 + c] : 0.f;
        Ts[r][c] = (n0 + r < HP) ? t[(size_t)(n0 + r) * 64 + c] : 0.f;
    }
    __syncthreads();
    int d = tid & 63, mg = tid >> 6;
    float acc[16];
#pragma unroll
    for (int i = 0; i < 16; i++) acc[i] = 0.f;
    for (int k = 0; k < 64; k++) {
        float tv = Ts[k][d];
#pragma unroll
        for (int mm = 0; mm < 16; mm++) acc[mm] = fmaf(Ws[mg * 16 + mm][k], tv, acc[mm]);
    }
#pragma unroll
    for (int mm = 0; mm < 16; mm++)
        atomicAdd(&tp[(size_t)(mg * 16 + mm) * 64 + d], acc[mm]);
}

// ---------------- epilogue ----------------
__global__ __launch_bounds__(256) void final_k(const float* __restrict__ tp,
        const float* __restrict__ e, const float* __restrict__ alog,
        const float* __restrict__ scal, const float* __restrict__ l3w,
        const float* __restrict__ l3b, const float* __restrict__ cw,
        const float* __restrict__ cb, float* __restrict__ out) {
    __shared__ float r1[64], hid[128];
    int tid = threadIdx.x;
    float Ma = scal[0], iZa = 1.f / scal[1];
    if (tid < 64) {
        float acc = 0.f;
        for (int m = 0; m < 64; m++) {
            float a = __expf(alog[m] - Ma) * iZa;
            acc += fabsf(tp[m * 64 + tid] - e[m * 64 + tid]) * a;
        }
        r1[tid] = fmaxf(acc, 0.f);
    }
    __syncthreads();
    if (tid < 128) {
        float acc = l3b[tid];
        for (int d = 0; d < 64; d++) acc = fmaf(r1[d], l3w[tid * 64 + d], acc);
        hid[tid] = fmaxf(acc, 0.f);
    }
    __syncthreads();
    if (tid < 2) {
        float acc = cb[tid];
        for (int j = 0; j < 128; j++) acc = fmaf(hid[j], cw[tid * 128 + j], acc);
        out[tid] = acc;
    }
}

// ---------------- weight packing ----------------
__global__ __launch_bounds__(256) void transpose_l1w_k(const float* __restrict__ w,
        float* __restrict__ wt) {
    int idx = blockIdx.x * 256 + threadIdx.x;
    if (idx >= KF * 64) return;
    int k = idx >> 6, j = idx & 63;
    wt[idx] = w[(size_t)j * KF + k];
}
__global__ __launch_bounds__(256) void pack_w2_k(const float* __restrict__ w,
        float* __restrict__ wp) {
    int idx = blockIdx.x * 256 + threadIdx.x;
    if (idx >= 12800) return;
    int co = idx & 31, rest = idx >> 5;
    wp[idx] = w[co * 400 + rest];
}
__global__ __launch_bounds__(256) void pack_w3_k(const float* __restrict__ w,
        float* __restrict__ wp) {
    int idx = blockIdx.x * 256 + threadIdx.x;
    if (idx >= 51200) return;
    int co = idx & 63, rest = idx >> 6;
    wp[idx] = w[co * 800 + rest];
}
__global__ __launch_bounds__(256) void pack_wih_k(const float* __restrict__ wih,
        const float* __restrict__ bih, const float* __restrict__ l1b,
        float* __restrict__ wiht, float* __restrict__ bc) {
    int idx = blockIdx.x * 256 + threadIdx.x;
    if (idx < 12288) {
        int g = idx % 192, k = idx / 192;
        wiht[idx] = wih[g * 64 + k];
    }
    if (idx < 192) {
        float acc = bih[idx];
#pragma unroll
        for (int k = 0; k < 64; k++) acc = fmaf(wih[idx * 64 + k], l1b[k], acc);
        bc[idx] = acc;
    }
}

// ---------------- host ----------------
extern "C" void kernel_launch(void* const* d_in, const int* in_sizes, int n_in,
                              void* d_out, int out_size, void* d_ws, size_t ws_size,
                              hipStream_t stream) {
    const float* ev    = (const float*)d_in[0];
    const float* tmpl  = (const float*)d_in[1];
    const float* w1    = (const float*)d_in[2];
    const float* b1    = (const float*)d_in[3];
    const float* w2    = (const float*)d_in[4];
    const float* b2    = (const float*)d_in[5];
    const float* w3    = (const float*)d_in[6];
    const float* b3    = (const float*)d_in[7];
    const float* l1w   = (const float*)d_in[8];
    const float* l1b   = (const float*)d_in[9];
    const float* wih   = (const float*)d_in[10];
    const float* whh   = (const float*)d_in[11];
    const float* bih   = (const float*)d_in[12];
    const float* bhh   = (const float*)d_in[13];
    const float* aw    = (const float*)d_in[14];
    const float* ab    = (const float*)d_in[15];
    const float* l3w   = (const float*)d_in[16];
    const float* l3b   = (const float*)d_in[17];
    const float* cw    = (const float*)d_in[18];
    const float* cb    = (const float*)d_in[19];
    float* out = (float*)d_out;
    (void)in_sizes; (void)n_in; (void)out_size;

    char* ws = (char*)d_ws;
    size_t off = 0;
    auto alloc = [&](size_t bytes) -> char* {
        char* p = ws + off;
        off += (bytes + 255) & ~(size_t)255;
        return p;
    };
    size_t szA = (size_t)C3 * H3 * W3 * 2;                 // fp16 conv3 out
    size_t szA1 = (size_t)C1 * H1 * W1 * 4;                // fp32 conv1 out
    if (szA1 > szA) szA = szA1;
    char*  A    = alloc(szA);
    float* B    = (float*)alloc((size_t)C2 * H2 * W2 * 4); // conv2 out / pooled
    float* Wt   = (float*)alloc((size_t)KF * 64 * 4);
    float* w2p  = (float*)alloc(12800 * 4);
    float* w3p  = (float*)alloc(51200 * 4);
    float* wiht = (float*)alloc(12288 * 4);
    float* bc   = (float*)alloc(256 * 4);
    float* L    = (float*)alloc((size_t)HP * 64 * 4);
    float* gi0  = (float*)alloc((size_t)HP * 192 * 4);
    float* gi1  = (float*)alloc((size_t)HP * 192 * 4);
    float* ebuf = (float*)alloc((size_t)HP * 64 * 4);
    float* tbuf = (float*)alloc((size_t)HP * 64 * 4);
    float* pM   = (float*)alloc((size_t)8 * HP * 4);
    float* pZ   = (float*)alloc((size_t)8 * HP * 4);
    float* Mn   = (float*)alloc(HP * 4);
    float* Zn   = (float*)alloc(HP * 4);
    float* Wm   = (float*)alloc((size_t)64 * HP * 4);
    float* alog = (float*)alloc(HP * 4);
    float* tpm  = (float*)alloc(64 * 64 * 4);
    float* scal = (float*)alloc(256);
    if (off > ws_size) return;   // workspace too small: bail loudly (validation fails)

    transpose_l1w_k<<<dim3((KF * 64 + 255) / 256), dim3(256), 0, stream>>>(l1w, Wt);
    pack_w2_k<<<dim3(50), dim3(256), 0, stream>>>(w2, w2p);
    pack_w3_k<<<dim3(200), dim3(256), 0, stream>>>(w3, w3p);
    pack_wih_k<<<dim3(48), dim3(256), 0, stream>>>(wih, bih, l1b, wiht, bc);

    for (int bsel = 0; bsel < 2; bsel++) {
        const float* xin = bsel ? tmpl : ev;
        float* gib = bsel ? gi1 : gi0;
        conv1_k<<<dim3((H1 * W1 + 255) / 256), dim3(256), 0, stream>>>(xin, w1, b1, (float*)A);
        conv2_k<<<dim3((H2 * W2 + 255) / 256), dim3(256), 0, stream>>>((const float*)A, w2p, b2, B);
        conv3_k<<<dim3((H3 * W3 + 255) / 256), dim3(256), 0, stream>>>(B, w3p, b3, (__half*)A);
        pool_k<<<dim3((C3 * HP * WPW + 255) / 256), dim3(256), 0, stream>>>((const __half*)A, B);
        hipMemsetAsync(L, 0, (size_t)HP * 64 * 4, stream);
        lin1_k<<<dim3(64, 4), dim3(256), 0, stream>>>(B, Wt, L);
        gi_k<<<dim3(HP), dim3(192), 0, stream>>>(L, wiht, bc, gib);
    }
    gru_k<<<dim3(2), dim3(192), 0, stream>>>(gi0, gi1, whh, bhh, ebuf, tbuf);
    astat_k<<<dim3(64, 8), dim3(256), 0, stream>>>(ebuf, tbuf, pM, pZ);
    attnlog_k<<<dim3(16), dim3(256), 0, stream>>>(ebuf, aw, ab, alog);
    reduce_k<<<dim3(17), dim3(256), 0, stream>>>(pM, pZ, Mn, Zn, alog, scal);
    wmat_k<<<dim3(16), dim3(256), 0, stream>>>(ebuf, tbuf, Mn, Zn, Wm);
    hipMemsetAsync(tpm, 0, 64 * 64 * 4, stream);
    tprim_k<<<dim3(64), dim3(256), 0, stream>>>(Wm, tbuf, tpm);
    final_k<<<dim3(1), dim3(256), 0, stream>>>(tpm, ebuf, alog, scal, l3w, l3b, cw, cb, out);
}